// Round 4
// baseline (906.923 us; speedup 1.0000x reference)
//
#include <hip/hip_runtime.h>
#include <hip/hip_bf16.h>

// ActLayer: out[b,o] = sum_{i,f} norm(sin(w_f x[b,i] + p_f)) * beta[f,o] * lamb[i,o] + bias[o]
//
// Round-6: round-3's verified structure (register-sin A-path, per-f barrier
// cadence UNCHANGED) + occupancy/latency fixes:
//   1. Split-K over i: grid 1024, each block does 4 of 8 i-tiles; partials
//      combined with fp32 atomicAdd (harness zeroes out before launch).
//      c_sh/bias added only by half-0 blocks. -> 4 blocks/CU resident.
//   2. brP shrunk [F][16][12]->[F][16][8] (LDS 45.6K -> 37.4K, fits 4/CU).
//   3. brP[f+1] prefetched into registers during step f (read-only LDS,
//      removes ~120cyc LDS latency from the per-f critical path).
//
// B=8192, I=512, F=64, O=512. BM=64, BN=128, i-chunk 64 (one f per K-step).
// 256 threads = 4 waves, wave w owns rows [m0+16w,+16) x 128 cols,
// mfma 16x16x32 bf16. Grid = 1024 -> 4 blocks/CU.

#define TB 256

typedef __attribute__((ext_vector_type(8))) short short8;
typedef __attribute__((ext_vector_type(4))) float floatx4;
typedef __attribute__((ext_vector_type(4))) unsigned int uintx4;
typedef __attribute__((ext_vector_type(4))) unsigned short ushort4t;

__device__ __forceinline__ unsigned pk_bf16(float a, float b) {
    __hip_bfloat162 h = __float22bfloat162_rn(make_float2(a, b));
    union { __hip_bfloat162 h2; unsigned u; } cv; cv.h2 = h; return cv.u;
}
__device__ __forceinline__ unsigned short f_to_bf16u(float v) {
    union { __hip_bfloat16 h; unsigned short u; } cv;
    cv.h = __float2bfloat16(v);
    return cv.u;
}
__device__ __forceinline__ float bf16u_to_f(unsigned short v) {
    union { unsigned u; float f; } cv; cv.u = ((unsigned)v) << 16; return cv.f;
}

// 8 bf16 sin values: sin(2*pi*(x*wfr + pfr)) for 8 register-resident x values.
__device__ __forceinline__ short8 sin_frag8(const float xv[8], float wfr, float pfr) {
    float s[8];
    #pragma unroll
    for (int j = 0; j < 8; ++j) {
        float arg = __builtin_amdgcn_fractf(fmaf(xv[j], wfr, pfr));
        s[j] = __builtin_amdgcn_sinf(arg);
    }
    union { uintx4 u; short8 h; } cv;
    cv.u.x = pk_bf16(s[0], s[1]); cv.u.y = pk_bf16(s[2], s[3]);
    cv.u.z = pk_bf16(s[4], s[5]); cv.u.w = pk_bf16(s[6], s[7]);
    return cv.h;
}

__global__ __launch_bounds__(TB, 4)
void actlayer_kernel(const float* __restrict__ x,
                     const float* __restrict__ freqs,
                     const float* __restrict__ phases,
                     const float* __restrict__ beta,
                     const float* __restrict__ lamb,
                     const float* __restrict__ bias,
                     float* __restrict__ out)
{
    constexpr int I = 512, F = 64, O = 512;
    constexpr int BN = 128;
    const int t  = threadIdx.x;
    const int bx = blockIdx.x;
    const int half = bx & 1;          // i-half: 0 -> i-tiles 0..3, 1 -> 4..7
    const int bn = (bx >> 1) & 3;     // 0..3
    const int bm = bx >> 3;           // 0..127
    const int n0 = bn * BN;
    const int m0 = bm * 64;

    __shared__ __align__(16) unsigned short L_sh[BN][72];     // lambda tile (bf16), per i-tile
    __shared__ __align__(16) unsigned short brP_sh[F][16][8]; // betaR bf16: [f][c=o%16][w=o/16]
    __shared__ float wrev_sh[F], prev_sh[F], r_sh[F], m_sh[F];
    __shared__ float c_sh[BN];
    __shared__ float slp_sh[2][BN];

    // ---- prologue: per-f normalization constants ----
    if (t < F) {
        float wq = freqs[t];
        float ph = phases[t];
        float e1 = expf(-0.5f * wq * wq);
        float mean = e1 * sinf(ph);
        float e2 = expf(-2.0f * wq * wq);
        float var = 0.5f - 0.5f * e2 * cosf(2.0f * ph) - mean * mean;
        float r = 1.0f / sqrtf(1e-3f + var);
        wrev_sh[t] = wq * 0.15915494309189535f;   // /2pi -> revolutions for v_sin
        prev_sh[t] = ph * 0.15915494309189535f;
        r_sh[t] = r;
        m_sh[t] = mean;
    }
    // sl[n] = sum_i lamb[i][n0+n] (full i-range) -- only half-0 blocks need it
    if (half == 0) {
        int n = t & 127, hh = t >> 7;
        float s = 0.f;
        const float* lp = lamb + (size_t)(hh * 256) * O + n0 + n;
        #pragma unroll 8
        for (int i = 0; i < 256; ++i) s += lp[(size_t)i * O];
        slp_sh[hh][n] = s;
    }
    __syncthreads();
    // brP[f][c][w] = beta[f][n0 + w*16 + c] * r_f   (bf16)
    #pragma unroll
    for (int j = 0; j < 32; ++j) {
        int e = t + TB * j;          // 0..8191
        int f = e >> 7;              // 0..63
        int rem = e & 127;
        int w = rem >> 4;            // 0..7
        int c = rem & 15;
        float bv = beta[f * O + n0 + w * 16 + c] * r_sh[f];
        brP_sh[f][c][w] = f_to_bf16u(bv);
    }
    __syncthreads();
    if (half == 0 && t < BN) {
        int c = t & 15, w = t >> 4;
        float sb = 0.f;
        #pragma unroll
        for (int f = 0; f < F; ++f) sb += bf16u_to_f(brP_sh[f][c][w]) * m_sh[f];
        c_sh[t] = bias[n0 + t] - sb * (slp_sh[0][t] + slp_sh[1][t]);
    }

    // ---- wave geometry: wave wid owns rows [m0+16*wid, +16), all 128 cols ----
    const int lane = t & 63;
    const int wid  = t >> 6;
    const int l15  = lane & 15;
    const int quad = lane >> 4;
    const int row  = m0 + wid * 16 + l15;

    floatx4 oacc[8];
    #pragma unroll
    for (int nt = 0; nt < 8; ++nt) oacc[nt] = (floatx4){0.f, 0.f, 0.f, 0.f};
    const floatx4 zero4 = (floatx4){0.f, 0.f, 0.f, 0.f};

    const int it0 = half * 4;
    #pragma unroll 1
    for (int it = it0; it < it0 + 4; ++it) {
        const int i0 = it * 64;
        // lambda tile -> LDS (bf16), once per i-tile.
        // Protected by the f=63 barrier of the previous i-tile (round-3 cadence).
        {
            int n  = t & 127;
            int kh = t >> 7;           // 0..1
            const float* lp = lamb + (size_t)(i0 + kh * 32) * O + n0 + n;
            float v[32];
            #pragma unroll
            for (int k = 0; k < 32; ++k) v[k] = lp[(size_t)k * O];
            #pragma unroll
            for (int rr = 0; rr < 4; ++rr) {
                uintx4 w4;
                w4.x = pk_bf16(v[rr*8+0], v[rr*8+1]);
                w4.y = pk_bf16(v[rr*8+2], v[rr*8+3]);
                w4.z = pk_bf16(v[rr*8+4], v[rr*8+5]);
                w4.w = pk_bf16(v[rr*8+6], v[rr*8+7]);
                *(uintx4*)&L_sh[n][kh * 32 + rr * 8] = w4;
            }
        }
        // x -> regs: exactly the 16 values this lane's A-frags need.
        float xr0[8], xr1[8];
        {
            const float* xp = x + (size_t)row * I + i0 + quad * 8;
            float4 a0 = *(const float4*)(xp);
            float4 a1 = *(const float4*)(xp + 4);
            float4 b0 = *(const float4*)(xp + 32);
            float4 b1 = *(const float4*)(xp + 36);
            xr0[0]=a0.x; xr0[1]=a0.y; xr0[2]=a0.z; xr0[3]=a0.w;
            xr0[4]=a1.x; xr0[5]=a1.y; xr0[6]=a1.z; xr0[7]=a1.w;
            xr1[0]=b0.x; xr1[1]=b0.y; xr1[2]=b0.z; xr1[3]=b0.w;
            xr1[4]=b1.x; xr1[5]=b1.y; xr1[6]=b1.z; xr1[7]=b1.w;
        }
        // A fragments for f=0 (registers)
        short8 af0 = sin_frag8(xr0, wrev_sh[0], prev_sh[0]);
        short8 af1 = sin_frag8(xr1, wrev_sh[0], prev_sh[0]);
        __syncthreads();   // L_sh ready
        // lambda fragments (f-invariant within this i-tile) -> registers
        short8 lf[2][8];
        #pragma unroll
        for (int kk = 0; kk < 2; ++kk)
            #pragma unroll
            for (int nt = 0; nt < 8; ++nt)
                lf[kk][nt] = *(const short8*)&L_sh[nt*16 + l15][kk*32 + quad*8];

        // betaR prefetch for f=0
        ushort4t bru0 = *(const ushort4t*)&brP_sh[0][l15][0];
        ushort4t bru1 = *(const ushort4t*)&brP_sh[0][l15][4];

        // ---- f-loop, round-3 cadence: sin(f+1)+brP(f+1) overlap MFMA(f),
        //      barrier per f (sync structure unchanged from verified kernel) ----
        #pragma unroll 2
        for (int f = 0; f < F; ++f) {
            // unpack this step's betaR values (prefetched)
            float br[8];
            #pragma unroll
            for (int q = 0; q < 4; ++q) {
                br[q]     = bf16u_to_f(bru0[q]);
                br[4 + q] = bf16u_to_f(bru1[q]);
            }
            // overlap: prefetch betaR + sin fragments for f+1 (registers only)
            short8 nf0 = af0, nf1 = af1;
            if (f < F - 1) {
                bru0 = *(const ushort4t*)&brP_sh[f + 1][l15][0];
                bru1 = *(const ushort4t*)&brP_sh[f + 1][l15][4];
                float wfr = wrev_sh[f + 1], pfr = prev_sh[f + 1];
                nf0 = sin_frag8(xr0, wfr, pfr);
                nf1 = sin_frag8(xr1, wfr, pfr);
            }
            // S_f = A_f @ Lambda ; out += betaR (.) S_f
            #pragma unroll
            for (int nt = 0; nt < 8; ++nt) {
                floatx4 s = __builtin_amdgcn_mfma_f32_16x16x32_bf16(
                    af0, lf[0][nt], zero4, 0, 0, 0);
                s = __builtin_amdgcn_mfma_f32_16x16x32_bf16(
                    af1, lf[1][nt], s, 0, 0, 0);
                oacc[nt] += br[nt] * s;
            }
            __syncthreads();
            af0 = nf0; af1 = nf1;
        }
    }

    // ---- epilogue: atomic partial-sum; half-0 adds the per-column constant ----
    #pragma unroll
    for (int nt = 0; nt < 8; ++nt) {
        int gn = n0 + nt*16 + l15;
        float cv = 0.f;
        if (half == 0) cv = c_sh[nt*16 + l15];
        int gm = m0 + wid*16 + quad*4;
        #pragma unroll
        for (int rg = 0; rg < 4; ++rg) {
            atomicAdd(&out[(size_t)(gm + rg) * O + gn], oacc[nt][rg] + cv);
        }
    }
}

extern "C" void kernel_launch(void* const* d_in, const int* in_sizes, int n_in,
                              void* d_out, int out_size, void* d_ws, size_t ws_size,
                              hipStream_t stream) {
    const float* x      = (const float*)d_in[0];
    const float* freqs  = (const float*)d_in[1];
    const float* phases = (const float*)d_in[2];
    const float* beta   = (const float*)d_in[3];
    const float* lamb   = (const float*)d_in[4];
    const float* bias   = (const float*)d_in[5];
    float* out = (float*)d_out;

    dim3 grid(1024);   // 128 m-blocks * 4 n-blocks * 2 i-halves
    dim3 block(TB);
    hipLaunchKernelGGL(actlayer_kernel, grid, block, 0, stream,
                       x, freqs, phases, beta, lamb, bias, out);
}